// Round 1
// baseline (2688.864 us; speedup 1.0000x reference)
//
#include <hip/hip_runtime.h>

#define BLK 64
#define RS 149   // LDS row stride in floats (odd -> 2-way bank aliasing only)

__device__ __forceinline__ float fast_sigmoid(float x) {
    return 1.0f / (1.0f + __expf(-x));
}
__device__ __forceinline__ float fast_tanh(float x) {
    float cx = fminf(fmaxf(x, -15.0f), 15.0f);
    float e = __expf(2.0f * cx);
    return (e - 1.0f) / (e + 1.0f);
}

__global__ __launch_bounds__(BLK, 1)
void ppo_agent_fused(
    const float* __restrict__ obs,          // (B,147)
    const int*   __restrict__ prev_action,  // (B,)
    const float* __restrict__ hidden,       // (B,128)
    const float* __restrict__ c1w, const float* __restrict__ c1b,   // (16,3,2,2),(16)
    const float* __restrict__ c2w, const float* __restrict__ c2b,   // (32,16,2,2),(32)
    const float* __restrict__ c3w, const float* __restrict__ c3b,   // (64,32,2,2),(64)
    const float* __restrict__ fcw, const float* __restrict__ fcb,   // (64,64),(64)
    const float* __restrict__ aemb,                                  // (7,16)
    const float* __restrict__ wih, const float* __restrict__ whh,   // (384,80),(384,128)
    const float* __restrict__ bih, const float* __restrict__ bhh,   // (384),(384)
    const float* __restrict__ a1w, const float* __restrict__ a1b,   // (64,128),(64)
    const float* __restrict__ a2w, const float* __restrict__ a2b,   // (7,64),(7)
    const float* __restrict__ cr1w, const float* __restrict__ cr1b, // (64,128),(64)
    const float* __restrict__ cr2w, const float* __restrict__ cr2b, // (1,64),(1)
    float* __restrict__ out, int B)
{
    __shared__ float lds[BLK * RS];
    const int tid = threadIdx.x;
    const int s   = blockIdx.x * BLK + tid;

    // ---- stage obs coalesced into LDS (padded rows) ----
    {
        const int base = blockIdx.x * BLK * 147;
        for (int idx = tid; idx < BLK * 147; idx += BLK) {
            int t = idx / 147;
            int i = idx - t * 147;
            lds[t * RS + i] = obs[base + idx];
        }
    }
    __syncthreads();

    // ---- img -> registers (compile-time indices) ----
    float img[147];
#pragma unroll
    for (int i = 0; i < 147; ++i) img[i] = lds[tid * RS + i];

    // ---- conv1 (3->16, 2x2, valid) + ReLU + maxpool 2x2 ----
    // pooled[c][py][px] written to own LDS row (runtime c sink)
    for (int c = 0; c < 16; ++c) {
        const float* w = c1w + c * 12;
        const float b = c1b[c];
#pragma unroll
        for (int py = 0; py < 3; ++py) {
#pragma unroll
            for (int px = 0; px < 3; ++px) {
                float mm = -1e30f;
#pragma unroll
                for (int dy = 0; dy < 2; ++dy) {
#pragma unroll
                    for (int dx = 0; dx < 2; ++dx) {
                        float acc = b;
#pragma unroll
                        for (int ci = 0; ci < 3; ++ci)
#pragma unroll
                            for (int ky = 0; ky < 2; ++ky)
#pragma unroll
                                for (int kx = 0; kx < 2; ++kx) {
                                    int y = 2 * py + dy + ky;
                                    int x = 2 * px + dx + kx;
                                    acc += img[(y * 7 + x) * 3 + ci] *
                                           w[(ci * 2 + ky) * 2 + kx];
                                }
                        mm = fmaxf(mm, acc);
                    }
                }
                lds[tid * RS + c * 9 + py * 3 + px] = fmaxf(mm, 0.0f);
            }
        }
    }

    // ---- pooled back to registers (compile-time indices) ----
    float pooled[144];
#pragma unroll
    for (int i = 0; i < 144; ++i) pooled[i] = lds[tid * RS + i];

    // ---- conv2 (16->32, 2x2) + ReLU, streamed into conv3 (32->64, 2x2) accumulators ----
    float acc3[64];
#pragma unroll
    for (int oc = 0; oc < 64; ++oc) acc3[oc] = c3b[oc];

    for (int c2 = 0; c2 < 32; ++c2) {
        float v[4];
#pragma unroll
        for (int oy = 0; oy < 2; ++oy) {
#pragma unroll
            for (int ox = 0; ox < 2; ++ox) {
                float acc = c2b[c2];
#pragma unroll
                for (int ci = 0; ci < 16; ++ci)
#pragma unroll
                    for (int ky = 0; ky < 2; ++ky)
#pragma unroll
                        for (int kx = 0; kx < 2; ++kx)
                            acc += pooled[ci * 9 + (oy + ky) * 3 + (ox + kx)] *
                                   c2w[((c2 * 16 + ci) * 2 + ky) * 2 + kx];
                v[oy * 2 + ox] = fmaxf(acc, 0.0f);
            }
        }
#pragma unroll
        for (int oc = 0; oc < 64; ++oc) {
            const float* w3 = c3w + (oc * 32 + c2) * 4;
            acc3[oc] += v[0] * w3[0] + v[1] * w3[1] + v[2] * w3[2] + v[3] * w3[3];
        }
    }
#pragma unroll
    for (int i = 0; i < 64; ++i) acc3[i] = fmaxf(acc3[i], 0.0f);

    // ---- fc (64->64) + ReLU, plus action embedding -> inp[80] ----
    float inp[80];
#pragma unroll
    for (int o = 0; o < 64; ++o) {
        float acc = fcb[o];
#pragma unroll
        for (int i = 0; i < 64; ++i) acc += acc3[i] * fcw[o * 64 + i];
        inp[o] = fmaxf(acc, 0.0f);
    }
    {
        const int pa = prev_action[s];
#pragma unroll
        for (int j = 0; j < 16; ++j) inp[64 + j] = aemb[pa * 16 + j];
    }

    // ---- stage hidden coalesced into LDS ----
    __syncthreads();   // all pooled reads done; safe to overwrite
    const int hbase = blockIdx.x * BLK * 128;
    for (int idx = tid; idx < BLK * 128; idx += BLK) {
        int t = idx >> 7;
        int i = idx & 127;
        lds[t * RS + i] = hidden[hbase + idx];
    }
    __syncthreads();

    float hreg[128];
#pragma unroll
    for (int i = 0; i < 128; ++i) hreg[i] = lds[tid * RS + i];

    // ---- GRUCell: gates r,z,n (torch order), h_new overwrites LDS row ----
    for (int k = 0; k < 128; ++k) {
        float xr = bih[k], xz = bih[k + 128], xn = bih[k + 256];
        const float* wr = wih + k * 80;
        const float* wz = wih + (k + 128) * 80;
        const float* wn = wih + (k + 256) * 80;
#pragma unroll
        for (int i = 0; i < 80; ++i) {
            xr += inp[i] * wr[i];
            xz += inp[i] * wz[i];
            xn += inp[i] * wn[i];
        }
        float hr = bhh[k], hz = bhh[k + 128], hn = bhh[k + 256];
        const float* vr = whh + k * 128;
        const float* vz = whh + (k + 128) * 128;
        const float* vn = whh + (k + 256) * 128;
#pragma unroll
        for (int i = 0; i < 128; ++i) {
            hr += hreg[i] * vr[i];
            hz += hreg[i] * vz[i];
            hn += hreg[i] * vn[i];
        }
        float r = fast_sigmoid(xr + hr);
        float z = fast_sigmoid(xz + hz);
        float n = fast_tanh(xn + r * hn);
        float hk = lds[tid * RS + k];
        lds[tid * RS + k] = (1.0f - z) * n + z * hk;
    }

    // ---- heads: read h_new from own LDS row (runtime i), 128 accumulators ----
    float accA[64], accC[64];
#pragma unroll
    for (int o = 0; o < 64; ++o) { accA[o] = a1b[o]; accC[o] = cr1b[o]; }
    for (int i = 0; i < 128; ++i) {
        float h = lds[tid * RS + i];
#pragma unroll
        for (int o = 0; o < 64; ++o) {
            accA[o] += h * a1w[o * 128 + i];
            accC[o] += h * cr1w[o * 128 + i];
        }
    }
#pragma unroll
    for (int o = 0; o < 64; ++o) {
        accA[o] = fast_tanh(accA[o]);
        accC[o] = fast_tanh(accC[o]);
    }
#pragma unroll
    for (int j = 0; j < 7; ++j) {
        float acc = a2b[j];
#pragma unroll
        for (int o = 0; o < 64; ++o) acc += accA[o] * a2w[j * 64 + o];
        out[s * 7 + j] = acc;
    }
    {
        float acc = cr2b[0];
#pragma unroll
        for (int o = 0; o < 64; ++o) acc += accC[o] * cr2w[o];
        out[(size_t)B * 7 + s] = acc;
    }

    // ---- coalesced h_new writeout ----
    __syncthreads();
    {
        float* hout = out + (size_t)B * 8;
        for (int idx = tid; idx < BLK * 128; idx += BLK) {
            hout[hbase + idx] = lds[(idx >> 7) * RS + (idx & 127)];
        }
    }
}

extern "C" void kernel_launch(void* const* d_in, const int* in_sizes, int n_in,
                              void* d_out, int out_size, void* d_ws, size_t ws_size,
                              hipStream_t stream) {
    const float* obs  = (const float*)d_in[0];
    const int*   pa   = (const int*)d_in[1];
    const float* hid  = (const float*)d_in[2];
    const float* c1w  = (const float*)d_in[3];
    const float* c1b  = (const float*)d_in[4];
    const float* c2w  = (const float*)d_in[5];
    const float* c2b  = (const float*)d_in[6];
    const float* c3w  = (const float*)d_in[7];
    const float* c3b  = (const float*)d_in[8];
    const float* fcw  = (const float*)d_in[9];
    const float* fcb  = (const float*)d_in[10];
    const float* aemb = (const float*)d_in[11];
    const float* wih  = (const float*)d_in[12];
    const float* whh  = (const float*)d_in[13];
    const float* bih  = (const float*)d_in[14];
    const float* bhh  = (const float*)d_in[15];
    const float* a1w  = (const float*)d_in[16];
    const float* a1b  = (const float*)d_in[17];
    const float* a2w  = (const float*)d_in[18];
    const float* a2b  = (const float*)d_in[19];
    const float* cr1w = (const float*)d_in[20];
    const float* cr1b = (const float*)d_in[21];
    const float* cr2w = (const float*)d_in[22];
    const float* cr2b = (const float*)d_in[23];

    const int B = in_sizes[1];            // prev_action count == batch
    const int grid = B / BLK;

    ppo_agent_fused<<<grid, BLK, 0, stream>>>(
        obs, pa, hid,
        c1w, c1b, c2w, c2b, c3w, c3b,
        fcw, fcb, aemb,
        wih, whh, bih, bhh,
        a1w, a1b, a2w, a2b, cr1w, cr1b, cr2w, cr2b,
        (float*)d_out, B);
}

// Round 2
// 553.049 us; speedup vs baseline: 4.8619x; 4.8619x over previous
//
#include <hip/hip_runtime.h>

typedef __attribute__((ext_vector_type(8))) short bf16x8;
typedef __attribute__((ext_vector_type(4))) float f32x4;

#define OFF_WX   0u
#define OFF_WH   73728u
#define OFF_WHD  172032u
#define OFF_X    262144u
#define WS_NEED  (262144u + 131072u*80u*2u)

__device__ __forceinline__ float fast_sigmoid(float x) {
    return 1.0f / (1.0f + __expf(-x));
}
__device__ __forceinline__ float fast_tanh(float x) {
    float cx = fminf(fmaxf(x, -15.0f), 15.0f);
    float e = __expf(2.0f * cx);
    return (e - 1.0f) / (e + 1.0f);
}
__device__ __forceinline__ unsigned short f2bf(float f) {
    unsigned u = __float_as_uint(f);
    unsigned r = u + 0x7FFFu + ((u >> 16) & 1u);
    return (unsigned short)(r >> 16);
}
__device__ __forceinline__ float bf2f(unsigned short h) {
    return __uint_as_float(((unsigned)h) << 16);
}
__device__ __forceinline__ unsigned packbf(float a, float b) {
    return (unsigned)f2bf(a) | ((unsigned)f2bf(b) << 16);
}

// ---------------------------------------------------------------------------
// Kernel 0: pack GEMM weights as bf16 MFMA B-fragments into d_ws.
// B-frag (16x16x32): lane l holds B[k = ks*32 + 8*(l>>4)+j][n = nt*16 + (l&15)]
// wx:  [g 0..2][nt 0..7][ks 0..2]  (K=96, zero-pad k>=80)   source Wih (384,80)
// wh:  [g 0..2][nt 0..7][ks 0..3]  (K=128)                  source Whh (384,128)
// whd: [head 0..1][nt 0..3][ks 0..3] (K=128)                source a1w/c1w (64,128)
// ---------------------------------------------------------------------------
__global__ __launch_bounds__(256, 1)
void prep_weights(const float* __restrict__ wih, const float* __restrict__ whh,
                  const float* __restrict__ a1w, const float* __restrict__ cr1w,
                  char* __restrict__ ws)
{
    int item = blockIdx.x * 256 + threadIdx.x;   // 12800 items total
    if (item >= 12800) return;
    int bid = item >> 6;
    int l = item & 63;
    int lr = l & 15;          // n within tile
    int kg = (l >> 4) * 8;    // k group base

    unsigned short v[8];
    char* dst;
    if (bid < 72) {               // wx
        int g = bid / 24, r1 = bid % 24, nt = r1 / 3, ks = r1 % 3;
        int n = nt * 16 + lr;
#pragma unroll
        for (int j = 0; j < 8; ++j) {
            int k = ks * 32 + kg + j;
            v[j] = (k < 80) ? f2bf(wih[(g * 128 + n) * 80 + k]) : (unsigned short)0;
        }
        dst = ws + OFF_WX + (((g * 8 + nt) * 3 + ks) << 10) + (l << 4);
    } else if (bid < 168) {       // wh
        int b2 = bid - 72;
        int g = b2 / 32, nt = (b2 % 32) / 4, ks = b2 % 4;
        int n = nt * 16 + lr;
#pragma unroll
        for (int j = 0; j < 8; ++j) {
            int k = ks * 32 + kg + j;
            v[j] = f2bf(whh[(g * 128 + n) * 128 + k]);
        }
        dst = ws + OFF_WH + (((g * 8 + nt) * 4 + ks) << 10) + (l << 4);
    } else {                      // heads
        int b3 = bid - 168;
        int head = b3 / 16, nt = (b3 % 16) / 4, ks = b3 % 4;
        int n = nt * 16 + lr;
        const float* w = head ? cr1w : a1w;
#pragma unroll
        for (int j = 0; j < 8; ++j) {
            int k = ks * 32 + kg + j;
            v[j] = f2bf(w[n * 128 + k]);
        }
        dst = ws + OFF_WHD + (((head * 4 + nt) * 4 + ks) << 10) + (l << 4);
    }
    unsigned u[4];
#pragma unroll
    for (int p = 0; p < 4; ++p) u[p] = (unsigned)v[2 * p] | ((unsigned)v[2 * p + 1] << 16);
    *(uint4*)dst = make_uint4(u[0], u[1], u[2], u[3]);
}

// ---------------------------------------------------------------------------
// Kernel 1: scalar conv front-end. 1 thread = 1 sample. Writes inp[80] bf16
// (packed as 40 u32, row-major B x 40) into d_ws at OFF_X.
// LDS: 64 rows x 300 B (bf16 staging: obs 147 / pooled 144 / X-out 40 u32).
// ---------------------------------------------------------------------------
__global__ __launch_bounds__(64, 2)
void conv_front(
    const float* __restrict__ obs, const int* __restrict__ prev_action,
    const float* __restrict__ c1w, const float* __restrict__ c1b,
    const float* __restrict__ c2w, const float* __restrict__ c2b,
    const float* __restrict__ c3w, const float* __restrict__ c3b,
    const float* __restrict__ fcw, const float* __restrict__ fcb,
    const float* __restrict__ aemb,
    char* __restrict__ ws)
{
    __shared__ char clds[64 * 300];
    const int tid = threadIdx.x;
    const int s = blockIdx.x * 64 + tid;

    // stage obs coalesced -> bf16 LDS rows
    {
        const size_t base = (size_t)blockIdx.x * 64 * 147;
        for (int idx = tid; idx < 64 * 147; idx += 64) {
            int r = idx / 147, c = idx - r * 147;
            *(unsigned short*)(clds + r * 300 + 2 * c) = f2bf(obs[base + idx]);
        }
    }
    __syncthreads();

    float img[147];
#pragma unroll
    for (int c = 0; c < 73; ++c) {
        unsigned u = *(const unsigned*)(clds + tid * 300 + 4 * c);
        img[2 * c] = bf2f((unsigned short)u);
        img[2 * c + 1] = bf2f((unsigned short)(u >> 16));
    }
    img[146] = bf2f(*(const unsigned short*)(clds + tid * 300 + 292));

    // conv1 (3->16, 2x2) + ReLU + maxpool -> bf16 LDS (own row, runtime c sink)
    for (int c = 0; c < 16; ++c) {
        const float* w = c1w + c * 12;
        const float b = c1b[c];
#pragma unroll
        for (int py = 0; py < 3; ++py) {
#pragma unroll
            for (int px = 0; px < 3; ++px) {
                float mm = -1e30f;
#pragma unroll
                for (int dy = 0; dy < 2; ++dy) {
#pragma unroll
                    for (int dx = 0; dx < 2; ++dx) {
                        float acc = b;
#pragma unroll
                        for (int ci = 0; ci < 3; ++ci)
#pragma unroll
                            for (int ky = 0; ky < 2; ++ky)
#pragma unroll
                                for (int kx = 0; kx < 2; ++kx) {
                                    int y = 2 * py + dy + ky;
                                    int x = 2 * px + dx + kx;
                                    acc += img[(y * 7 + x) * 3 + ci] *
                                           w[(ci * 2 + ky) * 2 + kx];
                                }
                        mm = fmaxf(mm, acc);
                    }
                }
                *(unsigned short*)(clds + tid * 300 + 2 * (c * 9 + py * 3 + px)) =
                    f2bf(fmaxf(mm, 0.0f));
            }
        }
    }

    float pooled[144];
#pragma unroll
    for (int c = 0; c < 72; ++c) {
        unsigned u = *(const unsigned*)(clds + tid * 300 + 4 * c);
        pooled[2 * c] = bf2f((unsigned short)u);
        pooled[2 * c + 1] = bf2f((unsigned short)(u >> 16));
    }

    // conv2 (16->32) + ReLU streamed into conv3 (32->64) accumulators
    float acc3[64];
#pragma unroll
    for (int oc = 0; oc < 64; ++oc) acc3[oc] = c3b[oc];

    for (int c2 = 0; c2 < 32; ++c2) {
        float v[4];
#pragma unroll
        for (int oy = 0; oy < 2; ++oy) {
#pragma unroll
            for (int ox = 0; ox < 2; ++ox) {
                float acc = c2b[c2];
#pragma unroll
                for (int ci = 0; ci < 16; ++ci)
#pragma unroll
                    for (int ky = 0; ky < 2; ++ky)
#pragma unroll
                        for (int kx = 0; kx < 2; ++kx)
                            acc += pooled[ci * 9 + (oy + ky) * 3 + (ox + kx)] *
                                   c2w[((c2 * 16 + ci) * 2 + ky) * 2 + kx];
                v[oy * 2 + ox] = fmaxf(acc, 0.0f);
            }
        }
#pragma unroll
        for (int oc = 0; oc < 64; ++oc) {
            const float* w3 = c3w + (oc * 32 + c2) * 4;
            acc3[oc] += v[0] * w3[0] + v[1] * w3[1] + v[2] * w3[2] + v[3] * w3[3];
        }
    }
#pragma unroll
    for (int i = 0; i < 64; ++i) acc3[i] = fmaxf(acc3[i], 0.0f);

    // fc + ReLU, append action embedding -> inp[80]
    float inp[80];
#pragma unroll
    for (int o = 0; o < 64; ++o) {
        float acc = fcb[o];
#pragma unroll
        for (int i = 0; i < 64; ++i) acc += acc3[i] * fcw[o * 64 + i];
        inp[o] = fmaxf(acc, 0.0f);
    }
    {
        const int pa = prev_action[s];
#pragma unroll
        for (int j = 0; j < 16; ++j) inp[64 + j] = aemb[pa * 16 + j];
    }

    // pack bf16 pairs into own row, then cooperative coalesced store
#pragma unroll
    for (int c = 0; c < 40; ++c)
        *(unsigned*)(clds + tid * 300 + 4 * c) = packbf(inp[2 * c], inp[2 * c + 1]);
    __syncthreads();
    {
        unsigned* wsx = (unsigned*)(ws + OFF_X);
        const size_t base = (size_t)blockIdx.x * 64 * 40;
        for (int idx = tid; idx < 64 * 40; idx += 64) {
            int r = idx / 40, c = idx - r * 40;
            wsx[base + idx] = *(const unsigned*)(clds + r * 300 + 4 * c);
        }
    }
}

// ---------------------------------------------------------------------------
// Kernel 2: MFMA GRU + heads. 512 threads = 8 waves, 128 samples/block,
// two 64-sample sub-tiles. Gate GEMM: wave w owns gate-col tile w (16 cols),
// all 4 row tiles; 4 acc sets (r, z, n_x, n_h). Heads: wave w -> head=w&1,
// n-tile=w>>1. Weight B-frags cached in VGPRs across sub-tiles.
// ---------------------------------------------------------------------------
#define SMX 0
#define SMH (64 * 192)
#define SMT (SMH + 64 * 256)
#define SMC (SMT + 64 * 128)

__global__ __launch_bounds__(512, 2)
void gru_heads(
    const float* __restrict__ hidden,
    const float* __restrict__ bih, const float* __restrict__ bhh,
    const float* __restrict__ a1b, const float* __restrict__ a2w,
    const float* __restrict__ a2b, const float* __restrict__ cr1b,
    const float* __restrict__ cr2w, const float* __restrict__ cr2b,
    const char* __restrict__ ws,
    float* __restrict__ out, int B)
{
    __shared__ char smem[SMC + 64 * 128];
    const int tid = threadIdx.x;
    const int l = tid & 63;
    const int w = tid >> 6;
    const int lr = l & 15;
    const int kg = (l >> 4) * 8;   // A/B k-group base within 32-k step

    const unsigned* wsx = (const unsigned*)(ws + OFF_X);
    float* outL = out;
    float* outV = out + (size_t)B * 7;
    float* outH = out + (size_t)B * 8;

    // ---- cache B fragments in registers (loop-invariant) ----
    bf16x8 BxR[3], BxZ[3], BxN[3];
#pragma unroll
    for (int ks = 0; ks < 3; ++ks) {
        BxR[ks] = *(const bf16x8*)(ws + OFF_WX + (((0 * 8 + w) * 3 + ks) << 10) + (l << 4));
        BxZ[ks] = *(const bf16x8*)(ws + OFF_WX + (((1 * 8 + w) * 3 + ks) << 10) + (l << 4));
        BxN[ks] = *(const bf16x8*)(ws + OFF_WX + (((2 * 8 + w) * 3 + ks) << 10) + (l << 4));
    }
    bf16x8 BhR[4], BhZ[4], BhN[4];
#pragma unroll
    for (int ks = 0; ks < 4; ++ks) {
        BhR[ks] = *(const bf16x8*)(ws + OFF_WH + (((0 * 8 + w) * 4 + ks) << 10) + (l << 4));
        BhZ[ks] = *(const bf16x8*)(ws + OFF_WH + (((1 * 8 + w) * 4 + ks) << 10) + (l << 4));
        BhN[ks] = *(const bf16x8*)(ws + OFF_WH + (((2 * 8 + w) * 4 + ks) << 10) + (l << 4));
    }
    const int head = w & 1, ntile = w >> 1;
    bf16x8 Bhd[4];
#pragma unroll
    for (int ks = 0; ks < 4; ++ks)
        Bhd[ks] = *(const bf16x8*)(ws + OFF_WHD + (((head * 4 + ntile) * 4 + ks) << 10) + (l << 4));

    // per-lane biases
    const int ncol = w * 16 + lr;                 // gate column 0..127
    const float bR = bih[ncol] + bhh[ncol];
    const float bZ = bih[128 + ncol] + bhh[128 + ncol];
    const float bNX = bih[256 + ncol];
    const float bNH = bhh[256 + ncol];
    const int hcol = ntile * 16 + lr;             // head column 0..63
    const float hbias = head ? cr1b[hcol] : a1b[hcol];

    for (int st = 0; st < 2; ++st) {
        const size_t rowBase = (size_t)blockIdx.x * 128 + st * 64;

        // ---- stage X (bf16, swizzle bits 4-5) ----
        for (int idx = tid; idx < 64 * 40; idx += 512) {
            int r = idx / 40, c = idx - r * 40;
            *(unsigned*)(smem + SMX + r * 192 + ((c * 4) ^ ((r & 3) << 4))) =
                wsx[(rowBase + r) * 40 + c];
        }
        {   // zero pad k=80..95
            int idx = tid;
            if (idx < 512) {
                int r = idx >> 3, c = 40 + (idx & 7);
                *(unsigned*)(smem + SMX + r * 192 + ((c * 4) ^ ((r & 3) << 4))) = 0u;
            }
        }
        // ---- stage H (fp32 global -> bf16, swizzle bits 4-6) ----
        for (int idx = tid; idx < 4096; idx += 512) {
            int r = idx >> 6, c2 = idx & 63;
            const float* hp = hidden + (rowBase + r) * 128 + 2 * c2;
            *(unsigned*)(smem + SMH + r * 256 + ((c2 * 4) ^ ((r & 7) << 4))) =
                packbf(hp[0], hp[1]);
        }
        __syncthreads();

        // ---- gate GEMMs ----
        f32x4 aR[4], aZ[4], aNX[4], aNH[4];
#pragma unroll
        for (int mt = 0; mt < 4; ++mt) { aR[mt] = 0.f; aZ[mt] = 0.f; aNX[mt] = 0.f; aNH[mt] = 0.f; }

#pragma unroll
        for (int ks = 0; ks < 3; ++ks) {
            bf16x8 A[4];
#pragma unroll
            for (int mt = 0; mt < 4; ++mt) {
                int row = mt * 16 + lr;
                int kb = (ks * 32 + kg) * 2;
                A[mt] = *(const bf16x8*)(smem + SMX + row * 192 + (kb ^ ((row & 3) << 4)));
            }
#pragma unroll
            for (int mt = 0; mt < 4; ++mt) {
                aR[mt] = __builtin_amdgcn_mfma_f32_16x16x32_bf16(A[mt], BxR[ks], aR[mt], 0, 0, 0);
                aZ[mt] = __builtin_amdgcn_mfma_f32_16x16x32_bf16(A[mt], BxZ[ks], aZ[mt], 0, 0, 0);
                aNX[mt] = __builtin_amdgcn_mfma_f32_16x16x32_bf16(A[mt], BxN[ks], aNX[mt], 0, 0, 0);
            }
        }
#pragma unroll
        for (int ks = 0; ks < 4; ++ks) {
            bf16x8 A[4];
#pragma unroll
            for (int mt = 0; mt < 4; ++mt) {
                int row = mt * 16 + lr;
                int kb = (ks * 32 + kg) * 2;
                A[mt] = *(const bf16x8*)(smem + SMH + row * 256 + (kb ^ ((row & 7) << 4)));
            }
#pragma unroll
            for (int mt = 0; mt < 4; ++mt) {
                aR[mt] = __builtin_amdgcn_mfma_f32_16x16x32_bf16(A[mt], BhR[ks], aR[mt], 0, 0, 0);
                aZ[mt] = __builtin_amdgcn_mfma_f32_16x16x32_bf16(A[mt], BhZ[ks], aZ[mt], 0, 0, 0);
                aNH[mt] = __builtin_amdgcn_mfma_f32_16x16x32_bf16(A[mt], BhN[ks], aNH[mt], 0, 0, 0);
            }
        }
        __syncthreads();   // all H reads done before in-place h_new writes

        // ---- elementwise GRU on fragments; h_new in-place (bf16) + f32 out ----
#pragma unroll
        for (int mt = 0; mt < 4; ++mt) {
#pragma unroll
            for (int i = 0; i < 4; ++i) {
                int row = mt * 16 + (l >> 4) * 4 + i;
                float R = aR[mt][i] + bR;
                float Z = aZ[mt][i] + bZ;
                float NX = aNX[mt][i] + bNX;
                float NH = aNH[mt][i] + bNH;
                float r = fast_sigmoid(R);
                float z = fast_sigmoid(Z);
                float n = fast_tanh(NX + r * NH);
                char* hp = smem + SMH + row * 256 + ((ncol * 2) ^ ((row & 7) << 4));
                float hold = bf2f(*(const unsigned short*)hp);
                float hn = (1.0f - z) * n + z * hold;
                outH[(rowBase + row) * 128 + ncol] = hn;
                *(unsigned short*)hp = f2bf(hn);
            }
        }
        __syncthreads();

        // ---- head GEMMs (h_new bf16 from LDS) ----
        f32x4 hc[4];
#pragma unroll
        for (int mt = 0; mt < 4; ++mt) hc[mt] = 0.f;
#pragma unroll
        for (int ks = 0; ks < 4; ++ks) {
            bf16x8 A[4];
#pragma unroll
            for (int mt = 0; mt < 4; ++mt) {
                int row = mt * 16 + lr;
                int kb = (ks * 32 + kg) * 2;
                A[mt] = *(const bf16x8*)(smem + SMH + row * 256 + (kb ^ ((row & 7) << 4)));
            }
#pragma unroll
            for (int mt = 0; mt < 4; ++mt)
                hc[mt] = __builtin_amdgcn_mfma_f32_16x16x32_bf16(A[mt], Bhd[ks], hc[mt], 0, 0, 0);
        }
        {
            char* T = smem + (head ? SMC : SMT);
#pragma unroll
            for (int mt = 0; mt < 4; ++mt) {
#pragma unroll
                for (int i = 0; i < 4; ++i) {
                    int row = mt * 16 + (l >> 4) * 4 + i;
                    float t = fast_tanh(hc[mt][i] + hbias);
                    *(unsigned short*)(T + row * 128 + ((hcol * 2) ^ ((row & 7) << 4))) = f2bf(t);
                }
            }
        }
        __syncthreads();

        // ---- final projections: thread t -> sample t>>3, output j=t&7 ----
        {
            int sample = tid >> 3, j = tid & 7;
            const char* T = smem + ((j == 7) ? SMC : SMT);
            const float* wrow = (j == 7) ? cr2w : (a2w + j * 64);
            float acc = (j == 7) ? cr2b[0] : a2b[j];
#pragma unroll
            for (int c = 0; c < 32; ++c) {
                unsigned u = *(const unsigned*)(T + sample * 128 + ((c * 4) ^ ((sample & 7) << 4)));
                acc += bf2f((unsigned short)u) * wrow[2 * c] +
                       bf2f((unsigned short)(u >> 16)) * wrow[2 * c + 1];
            }
            if (j < 7) outL[(rowBase + sample) * 7 + j] = acc;
            else       outV[rowBase + sample] = acc;
        }
        __syncthreads();
    }
}

// ---------------------------------------------------------------------------
// Fallback: round-1 fused scalar kernel (used only if ws_size too small).
// ---------------------------------------------------------------------------
__global__ __launch_bounds__(64, 1)
void ppo_agent_fused(
    const float* __restrict__ obs, const int* __restrict__ prev_action,
    const float* __restrict__ hidden,
    const float* __restrict__ c1w, const float* __restrict__ c1b,
    const float* __restrict__ c2w, const float* __restrict__ c2b,
    const float* __restrict__ c3w, const float* __restrict__ c3b,
    const float* __restrict__ fcw, const float* __restrict__ fcb,
    const float* __restrict__ aemb,
    const float* __restrict__ wih, const float* __restrict__ whh,
    const float* __restrict__ bih, const float* __restrict__ bhh,
    const float* __restrict__ a1w, const float* __restrict__ a1b,
    const float* __restrict__ a2w, const float* __restrict__ a2b,
    const float* __restrict__ cr1w, const float* __restrict__ cr1b,
    const float* __restrict__ cr2w, const float* __restrict__ cr2b,
    float* __restrict__ out, int B)
{
    __shared__ float lds[64 * 149];
    const int tid = threadIdx.x;
    const int s = blockIdx.x * 64 + tid;
    {
        const int base = blockIdx.x * 64 * 147;
        for (int idx = tid; idx < 64 * 147; idx += 64) {
            int t = idx / 147, i = idx - t * 147;
            lds[t * 149 + i] = obs[base + idx];
        }
    }
    __syncthreads();
    float img[147];
#pragma unroll
    for (int i = 0; i < 147; ++i) img[i] = lds[tid * 149 + i];
    for (int c = 0; c < 16; ++c) {
        const float* w = c1w + c * 12;
        const float b = c1b[c];
#pragma unroll
        for (int py = 0; py < 3; ++py)
#pragma unroll
            for (int px = 0; px < 3; ++px) {
                float mm = -1e30f;
#pragma unroll
                for (int dy = 0; dy < 2; ++dy)
#pragma unroll
                    for (int dx = 0; dx < 2; ++dx) {
                        float acc = b;
#pragma unroll
                        for (int ci = 0; ci < 3; ++ci)
#pragma unroll
                            for (int ky = 0; ky < 2; ++ky)
#pragma unroll
                                for (int kx = 0; kx < 2; ++kx)
                                    acc += img[((2 * py + dy + ky) * 7 + 2 * px + dx + kx) * 3 + ci] * w[(ci * 2 + ky) * 2 + kx];
                        mm = fmaxf(mm, acc);
                    }
                lds[tid * 149 + c * 9 + py * 3 + px] = fmaxf(mm, 0.0f);
            }
    }
    float pooled[144];
#pragma unroll
    for (int i = 0; i < 144; ++i) pooled[i] = lds[tid * 149 + i];
    float acc3[64];
#pragma unroll
    for (int oc = 0; oc < 64; ++oc) acc3[oc] = c3b[oc];
    for (int c2 = 0; c2 < 32; ++c2) {
        float v[4];
#pragma unroll
        for (int oy = 0; oy < 2; ++oy)
#pragma unroll
            for (int ox = 0; ox < 2; ++ox) {
                float acc = c2b[c2];
#pragma unroll
                for (int ci = 0; ci < 16; ++ci)
#pragma unroll
                    for (int ky = 0; ky < 2; ++ky)
#pragma unroll
                        for (int kx = 0; kx < 2; ++kx)
                            acc += pooled[ci * 9 + (oy + ky) * 3 + (ox + kx)] * c2w[((c2 * 16 + ci) * 2 + ky) * 2 + kx];
                v[oy * 2 + ox] = fmaxf(acc, 0.0f);
            }
#pragma unroll
        for (int oc = 0; oc < 64; ++oc) {
            const float* w3 = c3w + (oc * 32 + c2) * 4;
            acc3[oc] += v[0] * w3[0] + v[1] * w3[1] + v[2] * w3[2] + v[3] * w3[3];
        }
    }
#pragma unroll
    for (int i = 0; i < 64; ++i) acc3[i] = fmaxf(acc3[i], 0.0f);
    float inp[80];
#pragma unroll
    for (int o = 0; o < 64; ++o) {
        float acc = fcb[o];
#pragma unroll
        for (int i = 0; i < 64; ++i) acc += acc3[i] * fcw[o * 64 + i];
        inp[o] = fmaxf(acc, 0.0f);
    }
    {
        const int pa = prev_action[s];
#pragma unroll
        for (int j = 0; j < 16; ++j) inp[64 + j] = aemb[pa * 16 + j];
    }
    __syncthreads();
    const int hbase = blockIdx.x * 64 * 128;
    for (int idx = tid; idx < 64 * 128; idx += 64)
        lds[(idx >> 7) * 149 + (idx & 127)] = hidden[hbase + idx];
    __syncthreads();
    float hreg[128];
#pragma unroll
    for (int i = 0; i < 128; ++i) hreg[i] = lds[tid * 149 + i];
    for (int k = 0; k < 128; ++k) {
        float xr = bih[k], xz = bih[k + 128], xn = bih[k + 256];
        const float* wr = wih + k * 80;
        const float* wz = wih + (k + 128) * 80;
        const float* wn = wih + (k + 256) * 80;
#pragma unroll
        for (int i = 0; i < 80; ++i) { xr += inp[i] * wr[i]; xz += inp[i] * wz[i]; xn += inp[i] * wn[i]; }
        float hr = bhh[k], hz = bhh[k + 128], hn = bhh[k + 256];
        const float* vr = whh + k * 128;
        const float* vz = whh + (k + 128) * 128;
        const float* vn = whh + (k + 256) * 128;
#pragma unroll
        for (int i = 0; i < 128; ++i) { hr += hreg[i] * vr[i]; hz += hreg[i] * vz[i]; hn += hreg[i] * vn[i]; }
        float r = fast_sigmoid(xr + hr);
        float z = fast_sigmoid(xz + hz);
        float n = fast_tanh(xn + r * hn);
        float hk = lds[tid * 149 + k];
        lds[tid * 149 + k] = (1.0f - z) * n + z * hk;
    }
    float accA[64], accC[64];
#pragma unroll
    for (int o = 0; o < 64; ++o) { accA[o] = a1b[o]; accC[o] = cr1b[o]; }
    for (int i = 0; i < 128; ++i) {
        float h = lds[tid * 149 + i];
#pragma unroll
        for (int o = 0; o < 64; ++o) { accA[o] += h * a1w[o * 128 + i]; accC[o] += h * cr1w[o * 128 + i]; }
    }
#pragma unroll
    for (int o = 0; o < 64; ++o) { accA[o] = fast_tanh(accA[o]); accC[o] = fast_tanh(accC[o]); }
#pragma unroll
    for (int j = 0; j < 7; ++j) {
        float acc = a2b[j];
#pragma unroll
        for (int o = 0; o < 64; ++o) acc += accA[o] * a2w[j * 64 + o];
        out[s * 7 + j] = acc;
    }
    {
        float acc = cr2b[0];
#pragma unroll
        for (int o = 0; o < 64; ++o) acc += accC[o] * cr2w[o];
        out[(size_t)B * 7 + s] = acc;
    }
    __syncthreads();
    {
        float* hout = out + (size_t)B * 8;
        for (int idx = tid; idx < 64 * 128; idx += 64)
            hout[hbase + idx] = lds[(idx >> 7) * 149 + (idx & 127)];
    }
}

extern "C" void kernel_launch(void* const* d_in, const int* in_sizes, int n_in,
                              void* d_out, int out_size, void* d_ws, size_t ws_size,
                              hipStream_t stream) {
    const float* obs  = (const float*)d_in[0];
    const int*   pa   = (const int*)d_in[1];
    const float* hid  = (const float*)d_in[2];
    const float* c1w  = (const float*)d_in[3];
    const float* c1b  = (const float*)d_in[4];
    const float* c2w  = (const float*)d_in[5];
    const float* c2b  = (const float*)d_in[6];
    const float* c3w  = (const float*)d_in[7];
    const float* c3b  = (const float*)d_in[8];
    const float* fcw  = (const float*)d_in[9];
    const float* fcb  = (const float*)d_in[10];
    const float* aemb = (const float*)d_in[11];
    const float* wih  = (const float*)d_in[12];
    const float* whh  = (const float*)d_in[13];
    const float* bih  = (const float*)d_in[14];
    const float* bhh  = (const float*)d_in[15];
    const float* a1w  = (const float*)d_in[16];
    const float* a1b  = (const float*)d_in[17];
    const float* a2w  = (const float*)d_in[18];
    const float* a2b  = (const float*)d_in[19];
    const float* cr1w = (const float*)d_in[20];
    const float* cr1b = (const float*)d_in[21];
    const float* cr2w = (const float*)d_in[22];
    const float* cr2b = (const float*)d_in[23];

    const int B = in_sizes[1];

    if (ws_size < (size_t)WS_NEED) {
        ppo_agent_fused<<<B / 64, 64, 0, stream>>>(
            obs, pa, hid, c1w, c1b, c2w, c2b, c3w, c3b, fcw, fcb, aemb,
            wih, whh, bih, bhh, a1w, a1b, a2w, a2b, cr1w, cr1b, cr2w, cr2b,
            (float*)d_out, B);
        return;
    }

    char* ws = (char*)d_ws;
    prep_weights<<<50, 256, 0, stream>>>(wih, whh, a1w, cr1w, ws);
    conv_front<<<B / 64, 64, 0, stream>>>(obs, pa, c1w, c1b, c2w, c2b, c3w, c3b,
                                          fcw, fcb, aemb, ws);
    gru_heads<<<B / 128, 512, 0, stream>>>(hid, bih, bhh, a1b, a2w, a2b,
                                           cr1b, cr2w, cr2b, ws, (float*)d_out, B);
}

// Round 3
// 239.719 us; speedup vs baseline: 11.2167x; 2.3071x over previous
//
#include <hip/hip_runtime.h>

typedef __attribute__((ext_vector_type(8))) short bf16x8;
typedef __attribute__((ext_vector_type(4))) float f32x4;

// ---- ws layout (bytes): 420 B-fragments of 1KB, then embgate f32 ----
#define FRG_G1 0                 // 180 frags: nt<36, ks<5  (conv1 zero-expanded, K=160, N=576)
#define FRG_G2 (180*1024)        // 40:  nt<8,  ks<5  (conv2 zero-expanded, K=160, N=128)
#define FRG_G3 (220*1024)        // 16:  nt<4,  ks<4  (conv3 dense, K=128, N=64)
#define FRG_G4 (236*1024)        // 8:   nt<4,  ks<2  (fc, K=64, N=64)
#define FRG_GX (244*1024)        // 48:  nt<24, ks<2  (gates-x obs part, K=64, N=384)
#define FRG_GH (292*1024)        // 96:  nt<24, ks<4  (gates-h, K=128, N=384)
#define FRG_HD (388*1024)        // 32:  nt<8,  ks<4  (heads, K=128, N=128)
#define OFF_EMB (420*1024)       // 7*384 f32 = bih + aemb[a] @ Wx_act
#define WS_NEED (420*1024 + 7*384*4)

#define SWZ(r) (((r)&7)<<4)

__device__ __forceinline__ float fast_sigmoid(float x) {
    return 1.0f / (1.0f + __expf(-x));
}
__device__ __forceinline__ float fast_tanh(float x) {
    float cx = fminf(fmaxf(x, -15.0f), 15.0f);
    float e = __expf(2.0f * cx);
    return (e - 1.0f) / (e + 1.0f);
}
__device__ __forceinline__ unsigned short f2bf(float f) {
    unsigned u = __float_as_uint(f);
    unsigned r = u + 0x7FFFu + ((u >> 16) & 1u);
    return (unsigned short)(r >> 16);
}
__device__ __forceinline__ float bf2f(unsigned short h) {
    return __uint_as_float(((unsigned)h) << 16);
}
__device__ __forceinline__ unsigned packbf(float a, float b) {
    return (unsigned)f2bf(a) | ((unsigned)f2bf(b) << 16);
}

// ---------------------------------------------------------------------------
// prep: build all MFMA B-fragments + embgate. 1 block = 1 frag (64 lanes).
// B-frag convention (16x16x32, matches verified R2 kernel): lane l holds
// B[k = ks*32 + (l>>4)*8 + j][n = nt*16 + (l&15)], j<8, packed 4 u32.
// ---------------------------------------------------------------------------
__global__ __launch_bounds__(64, 4)
void prep(const float* __restrict__ c1w, const float* __restrict__ c2w,
          const float* __restrict__ c3w, const float* __restrict__ fcw,
          const float* __restrict__ wih, const float* __restrict__ whh,
          const float* __restrict__ bih,
          const float* __restrict__ a1w, const float* __restrict__ cr1w,
          const float* __restrict__ aemb,
          char* __restrict__ ws)
{
    const int b = blockIdx.x;
    const int l = threadIdx.x;

    if (b >= 420) {   // embgate
        int item = (b - 420) * 64 + l;
        if (item < 7 * 384) {
            int a = item / 384, n = item % 384;
            float acc = bih[n];
#pragma unroll
            for (int j = 0; j < 16; ++j) acc += aemb[a * 16 + j] * wih[n * 80 + 64 + j];
            ((float*)(ws + OFF_EMB))[item] = acc;
        }
        return;
    }

    const int lr = l & 15, kg = (l >> 4) * 8;
    float v[8];
#pragma unroll
    for (int j = 0; j < 8; ++j) v[j] = 0.0f;

    if (b < 180) {                           // G1: conv1 zero-expanded
        int nt = b / 5, ks = b % 5;
        int n = nt * 16 + lr;
        int c = n / 36, pos = n % 36, cy = pos / 6, cx = pos % 6;
#pragma unroll
        for (int j = 0; j < 8; ++j) {
            int k = ks * 32 + kg + j;
            if (k < 147) {
                int y = k / 21, r2 = k % 21, x = r2 / 3, ci = r2 % 3;
                int ky = y - cy, kx = x - cx;
                if (ky >= 0 && ky < 2 && kx >= 0 && kx < 2)
                    v[j] = c1w[((c * 3 + ci) * 2 + ky) * 2 + kx];
            }
        }
    } else if (b < 220) {                    // G2: conv2 zero-expanded
        int f = b - 180, nt = f / 5, ks = f % 5;
        int n = nt * 16 + lr;
        int c2 = n >> 2, oy = (n >> 1) & 1, ox = n & 1;
#pragma unroll
        for (int j = 0; j < 8; ++j) {
            int k = ks * 32 + kg + j;
            if (k < 144) {
                int c = k / 9, p9 = k % 9, py = p9 / 3, px = p9 % 3;
                int ky = py - oy, kx = px - ox;
                if (ky >= 0 && ky < 2 && kx >= 0 && kx < 2)
                    v[j] = c2w[((c2 * 16 + c) * 2 + ky) * 2 + kx];
            }
        }
    } else if (b < 236) {                    // G3: conv3 dense (K=128)
        int f = b - 220, nt = f / 4, ks = f % 4;
        int n = nt * 16 + lr;
#pragma unroll
        for (int j = 0; j < 8; ++j) v[j] = c3w[n * 128 + ks * 32 + kg + j];
    } else if (b < 244) {                    // G4: fc (K=64)
        int f = b - 236, nt = f / 2, ks = f % 2;
        int n = nt * 16 + lr;
#pragma unroll
        for (int j = 0; j < 8; ++j) v[j] = fcw[n * 64 + ks * 32 + kg + j];
    } else if (b < 292) {                    // GX: gates-x obs part (K=64)
        int f = b - 244, nt = f / 2, ks = f % 2;
        int n = nt * 16 + lr;
#pragma unroll
        for (int j = 0; j < 8; ++j) v[j] = wih[n * 80 + ks * 32 + kg + j];
    } else if (b < 388) {                    // GH: gates-h (K=128)
        int f = b - 292, nt = f / 4, ks = f % 4;
        int n = nt * 16 + lr;
#pragma unroll
        for (int j = 0; j < 8; ++j) v[j] = whh[n * 128 + ks * 32 + kg + j];
    } else {                                 // HD: heads (K=128, N=128)
        int f = b - 388, nt = f / 4, ks = f % 4;
        int n = nt * 16 + lr;
        const float* w = (n < 64) ? (a1w + n * 128) : (cr1w + (n - 64) * 128);
#pragma unroll
        for (int j = 0; j < 8; ++j) v[j] = w[ks * 32 + kg + j];
    }

    unsigned u[4];
#pragma unroll
    for (int p = 0; p < 4; ++p) u[p] = packbf(v[2 * p], v[2 * p + 1]);
    *(uint4*)(ws + b * 1024 + l * 16) = make_uint4(u[0], u[1], u[2], u[3]);
}

// ---------------------------------------------------------------------------
// fused_agent: whole network for a 64-sample tile. 512 threads = 8 waves.
// LDS: OBS/POOLED (24576) | BIG (73728): RAW -> X2,X3,X4,H,T | PA (256)
// All 2D LDS buffers: stride multiple of 128B, byte-offset XOR SWZ(row).
// ---------------------------------------------------------------------------
__global__ __launch_bounds__(512, 2)
void fused_agent(const float* __restrict__ obs, const int* __restrict__ pa_g,
                 const float* __restrict__ hidden,
                 const float* __restrict__ c1b, const float* __restrict__ c2b,
                 const float* __restrict__ c3b, const float* __restrict__ fcb,
                 const float* __restrict__ bhh,
                 const float* __restrict__ a1b, const float* __restrict__ cr1b,
                 const float* __restrict__ a2w, const float* __restrict__ a2b,
                 const float* __restrict__ cr2w, const float* __restrict__ cr2b,
                 const char* __restrict__ ws, float* __restrict__ out, int B)
{
    __shared__ char L[98560];
    char* OBSL = L;                 // 64 x 384B  (K=160 bf16)  -> later POOLED
    char* BIG  = L + 24576;         // 64 x 1152B (RAW 576 cols bf16)
    char* X2   = BIG;               // 64 x 256B  (K=128)
    char* X3   = BIG + 16384;       // 64 x 128B  (K=64)
    char* X4   = BIG + 24576;       // 64 x 128B  (K=64)
    char* HS   = BIG + 32768;       // 64 x 256B  (K=128)
    char* TS   = BIG + 49152;       // 64 x 256B  (actor 0-63 | critic 64-127)
    int* PA    = (int*)(L + 98304);

    const int tid = threadIdx.x;
    const int l = tid & 63, w = tid >> 6;
    const int lr = l & 15, kg = (l >> 4) * 8;
    const size_t rowBase = (size_t)blockIdx.x * 64;
    const float* EMB = (const float*)(ws + OFF_EMB);

    // ---- S0: stage obs (f32 -> bf16, K pad 147->160) + prev_action ----
    for (int idx = tid; idx < 64 * 80; idx += 512) {
        int r = idx / 80, c = idx % 80;
        int k0 = 2 * c;
        const float* src = obs + (rowBase + r) * 147;
        float v0 = (k0 < 147) ? src[k0] : 0.0f;
        float v1 = (k0 + 1 < 147) ? src[k0 + 1] : 0.0f;
        *(unsigned*)(OBSL + r * 384 + ((4 * c) ^ SWZ(r))) = packbf(v0, v1);
    }
    if (tid < 64) PA[tid] = pa_g[rowBase + tid];
    __syncthreads();

    // ---- S1: G1 = OBS @ W1e  (N=576, waves take nt = w+8i) ----
    {
        f32x4 acc[5][4];
#pragma unroll
        for (int i = 0; i < 5; ++i)
#pragma unroll
            for (int mt = 0; mt < 4; ++mt) acc[i][mt] = (f32x4)0.0f;

#pragma unroll
        for (int ks = 0; ks < 5; ++ks) {
            bf16x8 A[4];
#pragma unroll
            for (int mt = 0; mt < 4; ++mt) {
                int row = mt * 16 + lr;
                A[mt] = *(const bf16x8*)(OBSL + row * 384 + (((ks * 32 + kg) * 2) ^ SWZ(row)));
            }
#pragma unroll
            for (int i = 0; i < 5; ++i) {
                int nt = w + 8 * i;
                if (nt < 36) {
                    bf16x8 Bf = *(const bf16x8*)(ws + FRG_G1 + (nt * 5 + ks) * 1024 + l * 16);
#pragma unroll
                    for (int mt = 0; mt < 4; ++mt)
                        acc[i][mt] = __builtin_amdgcn_mfma_f32_16x16x32_bf16(A[mt], Bf, acc[i][mt], 0, 0, 0);
                }
            }
        }
#pragma unroll
        for (int i = 0; i < 5; ++i) {
            int nt = w + 8 * i;
            if (nt < 36) {
                int col = nt * 16 + lr;
#pragma unroll
                for (int mt = 0; mt < 4; ++mt)
#pragma unroll
                    for (int q = 0; q < 4; ++q) {
                        int row = mt * 16 + (l >> 4) * 4 + q;
                        *(unsigned short*)(BIG + row * 1152 + ((col * 2) ^ SWZ(row))) =
                            f2bf(acc[i][mt][q]);
                    }
            }
        }
    }
    __syncthreads();

    // ---- S2: maxpool + bias + relu -> POOLED (OBS region), K pad 144->160 ----
    for (int idx = tid; idx < 64 * 144; idx += 512) {
        int r = idx / 144, pc = idx % 144;
        int c = pc / 9, p9 = pc % 9, py = p9 / 3, px = p9 % 3;
        int cb = c * 36 + (2 * py) * 6 + 2 * px;
        const char* rb = BIG + r * 1152;
        float m0 = bf2f(*(const unsigned short*)(rb + (((cb + 0) * 2) ^ SWZ(r))));
        float m1 = bf2f(*(const unsigned short*)(rb + (((cb + 1) * 2) ^ SWZ(r))));
        float m2 = bf2f(*(const unsigned short*)(rb + (((cb + 6) * 2) ^ SWZ(r))));
        float m3 = bf2f(*(const unsigned short*)(rb + (((cb + 7) * 2) ^ SWZ(r))));
        float m = fmaxf(fmaxf(m0, m1), fmaxf(m2, m3)) + c1b[c];
        *(unsigned short*)(OBSL + r * 384 + ((pc * 2) ^ SWZ(r))) = f2bf(fmaxf(m, 0.0f));
    }
    for (int idx = tid; idx < 64 * 16; idx += 512) {
        int r = idx >> 4, k = 144 + (idx & 15);
        *(unsigned short*)(OBSL + r * 384 + ((k * 2) ^ SWZ(r))) = 0;
    }
    __syncthreads();

    // ---- S3: stage H (loads issued early) + G2 = POOLED @ W2e (nt = w) ----
    {
        float2 hv[8];
#pragma unroll
        for (int t = 0; t < 8; ++t) {
            int idx = tid + t * 512;
            int r = idx >> 6, c2 = idx & 63;
            hv[t] = *(const float2*)(hidden + (rowBase + r) * 128 + 2 * c2);
        }

        f32x4 acc[4];
#pragma unroll
        for (int mt = 0; mt < 4; ++mt) acc[mt] = (f32x4)0.0f;
#pragma unroll
        for (int ks = 0; ks < 5; ++ks) {
            bf16x8 A[4];
#pragma unroll
            for (int mt = 0; mt < 4; ++mt) {
                int row = mt * 16 + lr;
                A[mt] = *(const bf16x8*)(OBSL + row * 384 + (((ks * 32 + kg) * 2) ^ SWZ(row)));
            }
            bf16x8 Bf = *(const bf16x8*)(ws + FRG_G2 + (w * 5 + ks) * 1024 + l * 16);
#pragma unroll
            for (int mt = 0; mt < 4; ++mt)
                acc[mt] = __builtin_amdgcn_mfma_f32_16x16x32_bf16(A[mt], Bf, acc[mt], 0, 0, 0);
        }

#pragma unroll
        for (int t = 0; t < 8; ++t) {
            int idx = tid + t * 512;
            int r = idx >> 6, c2 = idx & 63;
            *(unsigned*)(HS + r * 256 + ((4 * c2) ^ SWZ(r))) = packbf(hv[t].x, hv[t].y);
        }

        int col = w * 16 + lr;
        float bias = c2b[col >> 2];
#pragma unroll
        for (int mt = 0; mt < 4; ++mt)
#pragma unroll
            for (int q = 0; q < 4; ++q) {
                int row = mt * 16 + (l >> 4) * 4 + q;
                *(unsigned short*)(X2 + row * 256 + ((col * 2) ^ SWZ(row))) =
                    f2bf(fmaxf(acc[mt][q] + bias, 0.0f));
            }
    }
    __syncthreads();

    // ---- S4: G3 = X2 @ W3 (N=64: nt=w&3, mt half = w>>2) ----
    {
        int nt = w & 3, mh = (w >> 2) * 2;
        f32x4 acc[2];
        acc[0] = (f32x4)0.0f; acc[1] = (f32x4)0.0f;
#pragma unroll
        for (int ks = 0; ks < 4; ++ks) {
            bf16x8 Bf = *(const bf16x8*)(ws + FRG_G3 + (nt * 4 + ks) * 1024 + l * 16);
#pragma unroll
            for (int m2 = 0; m2 < 2; ++m2) {
                int row = (mh + m2) * 16 + lr;
                bf16x8 A = *(const bf16x8*)(X2 + row * 256 + (((ks * 32 + kg) * 2) ^ SWZ(row)));
                acc[m2] = __builtin_amdgcn_mfma_f32_16x16x32_bf16(A, Bf, acc[m2], 0, 0, 0);
            }
        }
        int col = nt * 16 + lr;
        float bias = c3b[col];
#pragma unroll
        for (int m2 = 0; m2 < 2; ++m2)
#pragma unroll
            for (int q = 0; q < 4; ++q) {
                int row = (mh + m2) * 16 + (l >> 4) * 4 + q;
                *(unsigned short*)(X3 + row * 128 + ((col * 2) ^ SWZ(row))) =
                    f2bf(fmaxf(acc[m2][q] + bias, 0.0f));
            }
    }
    __syncthreads();

    // ---- S5: G4 = X3 @ W4 (fc, K=64) -> X4 = obs_enc ----
    {
        int nt = w & 3, mh = (w >> 2) * 2;
        f32x4 acc[2];
        acc[0] = (f32x4)0.0f; acc[1] = (f32x4)0.0f;
#pragma unroll
        for (int ks = 0; ks < 2; ++ks) {
            bf16x8 Bf = *(const bf16x8*)(ws + FRG_G4 + (nt * 2 + ks) * 1024 + l * 16);
#pragma unroll
            for (int m2 = 0; m2 < 2; ++m2) {
                int row = (mh + m2) * 16 + lr;
                bf16x8 A = *(const bf16x8*)(X3 + row * 128 + (((ks * 32 + kg) * 2) ^ SWZ(row)));
                acc[m2] = __builtin_amdgcn_mfma_f32_16x16x32_bf16(A, Bf, acc[m2], 0, 0, 0);
            }
        }
        int col = nt * 16 + lr;
        float bias = fcb[col];
#pragma unroll
        for (int m2 = 0; m2 < 2; ++m2)
#pragma unroll
            for (int q = 0; q < 4; ++q) {
                int row = (mh + m2) * 16 + (l >> 4) * 4 + q;
                *(unsigned short*)(X4 + row * 128 + ((col * 2) ^ SWZ(row))) =
                    f2bf(fmaxf(acc[m2][q] + bias, 0.0f));
            }
    }
    __syncthreads();

    // ---- S6: GRU gates. wave w: nt = w (r), w+8 (z), w+16 (n); col = w*16+lr ----
    {
        f32x4 aRZ[2][4], aNX[4], aNH[4];
#pragma unroll
        for (int mt = 0; mt < 4; ++mt) {
            aRZ[0][mt] = (f32x4)0.0f; aRZ[1][mt] = (f32x4)0.0f;
            aNX[mt] = (f32x4)0.0f;    aNH[mt] = (f32x4)0.0f;
        }
        // gates-x: K=64 from X4
#pragma unroll
        for (int ks = 0; ks < 2; ++ks) {
            bf16x8 A[4];
#pragma unroll
            for (int mt = 0; mt < 4; ++mt) {
                int row = mt * 16 + lr;
                A[mt] = *(const bf16x8*)(X4 + row * 128 + (((ks * 32 + kg) * 2) ^ SWZ(row)));
            }
#pragma unroll
            for (int g = 0; g < 3; ++g) {
                int nt = w + 8 * g;
                bf16x8 Bf = *(const bf16x8*)(ws + FRG_GX + (nt * 2 + ks) * 1024 + l * 16);
#pragma unroll
                for (int mt = 0; mt < 4; ++mt) {
                    if (g < 2) aRZ[g][mt] = __builtin_amdgcn_mfma_f32_16x16x32_bf16(A[mt], Bf, aRZ[g][mt], 0, 0, 0);
                    else       aNX[mt]   = __builtin_amdgcn_mfma_f32_16x16x32_bf16(A[mt], Bf, aNX[mt], 0, 0, 0);
                }
            }
        }
        // gates-h: K=128 from HS
#pragma unroll
        for (int ks = 0; ks < 4; ++ks) {
            bf16x8 A[4];
#pragma unroll
            for (int mt = 0; mt < 4; ++mt) {
                int row = mt * 16 + lr;
                A[mt] = *(const bf16x8*)(HS + row * 256 + (((ks * 32 + kg) * 2) ^ SWZ(row)));
            }
#pragma unroll
            for (int g = 0; g < 3; ++g) {
                int nt = w + 8 * g;
                bf16x8 Bf = *(const bf16x8*)(ws + FRG_GH + (nt * 4 + ks) * 1024 + l * 16);
#pragma unroll
                for (int mt = 0; mt < 4; ++mt) {
                    if (g < 2) aRZ[g][mt] = __builtin_amdgcn_mfma_f32_16x16x32_bf16(A[mt], Bf, aRZ[g][mt], 0, 0, 0);
                    else       aNH[mt]   = __builtin_amdgcn_mfma_f32_16x16x32_bf16(A[mt], Bf, aNH[mt], 0, 0, 0);
                }
            }
        }
        __syncthreads();   // all waves' H reads complete before in-place update

        const int nc = w * 16 + lr;
        const float bR = bhh[nc], bZ = bhh[128 + nc], bN = bhh[256 + nc];
#pragma unroll
        for (int mt = 0; mt < 4; ++mt)
#pragma unroll
            for (int q = 0; q < 4; ++q) {
                int row = mt * 16 + (l >> 4) * 4 + q;
                int a = PA[row];
                const float* eg = EMB + a * 384;
                float R  = aRZ[0][mt][q] + bR + eg[nc];
                float Z  = aRZ[1][mt][q] + bZ + eg[128 + nc];
                float NX = aNX[mt][q] + eg[256 + nc];
                float NH = aNH[mt][q] + bN;
                float rg = fast_sigmoid(R);
                float zg = fast_sigmoid(Z);
                float ng = fast_tanh(NX + rg * NH);
                char* hp = HS + row * 256 + ((nc * 2) ^ SWZ(row));
                float hold = bf2f(*(const unsigned short*)hp);
                float hn = (1.0f - zg) * ng + zg * hold;
                out[(size_t)B * 8 + (rowBase + row) * 128 + nc] = hn;
                *(unsigned short*)hp = f2bf(hn);
            }
    }
    __syncthreads();

    // ---- S7: heads = h_new @ [a1w | cr1w], tanh -> TS ----
    {
        f32x4 acc[4];
#pragma unroll
        for (int mt = 0; mt < 4; ++mt) acc[mt] = (f32x4)0.0f;
#pragma unroll
        for (int ks = 0; ks < 4; ++ks) {
            bf16x8 A[4];
#pragma unroll
            for (int mt = 0; mt < 4; ++mt) {
                int row = mt * 16 + lr;
                A[mt] = *(const bf16x8*)(HS + row * 256 + (((ks * 32 + kg) * 2) ^ SWZ(row)));
            }
            bf16x8 Bf = *(const bf16x8*)(ws + FRG_HD + (w * 4 + ks) * 1024 + l * 16);
#pragma unroll
            for (int mt = 0; mt < 4; ++mt)
                acc[mt] = __builtin_amdgcn_mfma_f32_16x16x32_bf16(A[mt], Bf, acc[mt], 0, 0, 0);
        }
        int col = w * 16 + lr;
        float hb = (col < 64) ? a1b[col] : cr1b[col - 64];
#pragma unroll
        for (int mt = 0; mt < 4; ++mt)
#pragma unroll
            for (int q = 0; q < 4; ++q) {
                int row = mt * 16 + (l >> 4) * 4 + q;
                *(unsigned short*)(TS + row * 256 + ((col * 2) ^ SWZ(row))) =
                    f2bf(fast_tanh(acc[mt][q] + hb));
            }
    }
    __syncthreads();

    // ---- S8: final projections. thread: sample = tid>>3, j = tid&7 ----
    {
        int sm = tid >> 3, j = tid & 7;
        float acc;
        const float* wrow;
        int cbase;
        if (j < 7) { acc = a2b[j];  wrow = a2w + j * 64; cbase = 0; }
        else       { acc = cr2b[0]; wrow = cr2w;         cbase = 64; }
#pragma unroll
        for (int c = 0; c < 32; ++c) {
            unsigned u = *(const unsigned*)(TS + sm * 256 + (((cbase + 2 * c) * 2) ^ SWZ(sm)));
            acc += bf2f((unsigned short)u) * wrow[2 * c] +
                   bf2f((unsigned short)(u >> 16)) * wrow[2 * c + 1];
        }
        if (j < 7) out[(rowBase + sm) * 7 + j] = acc;
        else       out[(size_t)B * 7 + rowBase + sm] = acc;
    }
}

extern "C" void kernel_launch(void* const* d_in, const int* in_sizes, int n_in,
                              void* d_out, int out_size, void* d_ws, size_t ws_size,
                              hipStream_t stream) {
    const float* obs  = (const float*)d_in[0];
    const int*   pa   = (const int*)d_in[1];
    const float* hid  = (const float*)d_in[2];
    const float* c1w  = (const float*)d_in[3];
    const float* c1b  = (const float*)d_in[4];
    const float* c2w  = (const float*)d_in[5];
    const float* c2b  = (const float*)d_in[6];
    const float* c3w  = (const float*)d_in[7];
    const float* c3b  = (const float*)d_in[8];
    const float* fcw  = (const float*)d_in[9];
    const float* fcb  = (const float*)d_in[10];
    const float* aemb = (const float*)d_in[11];
    const float* wih  = (const float*)d_in[12];
    const float* whh  = (const float*)d_in[13];
    const float* bih  = (const float*)d_in[14];
    const float* bhh  = (const float*)d_in[15];
    const float* a1w  = (const float*)d_in[16];
    const float* a1b  = (const float*)d_in[17];
    const float* a2w  = (const float*)d_in[18];
    const float* a2b  = (const float*)d_in[19];
    const float* cr1w = (const float*)d_in[20];
    const float* cr1b = (const float*)d_in[21];
    const float* cr2w = (const float*)d_in[22];
    const float* cr2b = (const float*)d_in[23];

    const int B = in_sizes[1];
    char* ws = (char*)d_ws;

    prep<<<462, 64, 0, stream>>>(c1w, c2w, c3w, fcw, wih, whh, bih, a1w, cr1w, aemb, ws);
    fused_agent<<<B / 64, 512, 0, stream>>>(
        obs, pa, hid, c1b, c2b, c3b, fcb, bhh, a1b, cr1b,
        a2w, a2b, cr2w, cr2b, ws, (float*)d_out, B);
}